// Round 9
// baseline (1248.877 us; speedup 1.0000x reference)
//
#include <hip/hip_runtime.h>
#include <hip/hip_bf16.h>

typedef __attribute__((ext_vector_type(8))) __bf16 bf16x8;
typedef __attribute__((ext_vector_type(4))) float f32x4;
typedef __attribute__((ext_vector_type(16))) float f32x16;
typedef __attribute__((ext_vector_type(4))) unsigned int u32x4;

#define SEQ 2048
#define NH 32
#define NKV 8
#define HD 128

__device__ __forceinline__ ushort f2bf(float f) {
  unsigned u = __builtin_bit_cast(unsigned, f);
  unsigned r = (u + 0x7fffu + ((u >> 16) & 1u)) >> 16;  // RNE
  return (ushort)r;
}
__device__ __forceinline__ float bf2f(ushort h) {
  return __builtin_bit_cast(float, ((unsigned)h) << 16);
}
__device__ __forceinline__ unsigned cvt_pk_bf16(float lo, float hi) {
  unsigned r;
  asm("v_cvt_pk_bf16_f32 %0, %1, %2" : "=v"(r) : "v"(lo), "v"(hi));
  return r;
}
__device__ __forceinline__ float exp2_fast(float x) {  // scores are in log2 domain
  float r;
  asm("v_exp_f32 %0, %1" : "=v"(r) : "v"(x));
  return r;
}
__device__ __forceinline__ void gload16(const void* g, void* l) {
  __builtin_amdgcn_global_load_lds(
      (const __attribute__((address_space(1))) void*)g,
      (__attribute__((address_space(3))) void*)l, 16, 0, 0);
}

// ---------------- fused f32 -> bf16 convert (all 5 inputs; outputs contiguous) ----------------
__global__ __launch_bounds__(256) void f2bf5_kernel(const float4* __restrict__ hs,
                                                    const float4* __restrict__ wq,
                                                    const float4* __restrict__ wk,
                                                    const float4* __restrict__ wv,
                                                    const float4* __restrict__ wo,
                                                    ushort4* __restrict__ out) {
  unsigned i = blockIdx.x * 256 + threadIdx.x;  // < 14680064
  const float4* src;
  unsigned j;
  if (i < 4194304u) { src = hs; j = i; }
  else if (i < 8388608u) { src = wq; j = i - 4194304u; }
  else if (i < 9437184u) { src = wk; j = i - 8388608u; }
  else if (i < 10485760u) { src = wv; j = i - 9437184u; }
  else { src = wo; j = i - 10485760u; }
  float4 v = src[j];
  ushort4 o;
  o.x = f2bf(v.x); o.y = f2bf(v.y); o.z = f2bf(v.z); o.w = f2bf(v.w);
  out[i] = o;
}

// ---------------- 128^2 GEMM (m97 structure): C = A * B^T ----------------
template <int OUTF32>
__global__ __launch_bounds__(256) void gemm_bt_kernel(const ushort* __restrict__ A,
                                                      const ushort* __restrict__ B,
                                                      void* __restrict__ C,
                                                      int M, int N, int K) {
  __shared__ ushort As[2][128 * 32];
  __shared__ ushort Bs[2][128 * 32];
  const int tid = threadIdx.x;
  const int w = tid >> 6, l = tid & 63;
  const int lr = l & 15, lc = l >> 4;
  const int bx = blockIdx.x, by = blockIdx.y;
  const int wr = w >> 1, wc = w & 1;

  f32x4 z = {0.f, 0.f, 0.f, 0.f};
  f32x4 acc[4][4];
#pragma unroll
  for (int i = 0; i < 4; ++i)
#pragma unroll
    for (int j = 0; j < 4; ++j) acc[i][j] = z;

  const ushort* aSrc = A + (size_t)(by * 128 + 32 * w + (l >> 2)) * K + (l & 3) * 8;
  const ushort* bSrc = B + (size_t)(bx * 128 + 32 * w + (l >> 2)) * K + (l & 3) * 8;
  const int ldsOff = (32 * w) * 32;

#pragma unroll
  for (int q = 0; q < 2; ++q) {
    gload16(aSrc + (size_t)q * 16 * K, &As[0][ldsOff + q * 512]);
    gload16(bSrc + (size_t)q * 16 * K, &Bs[0][ldsOff + q * 512]);
  }
  __syncthreads();

  const int nk = K >> 5;
  int cur = 0;
  for (int kt = 0; kt < nk; ++kt) {
    if (kt + 1 < nk) {
      const ushort* a2 = aSrc + (size_t)(kt + 1) * 32;
      const ushort* b2 = bSrc + (size_t)(kt + 1) * 32;
#pragma unroll
      for (int q = 0; q < 2; ++q) {
        gload16(a2 + (size_t)q * 16 * K, &As[cur ^ 1][ldsOff + q * 512]);
        gload16(b2 + (size_t)q * 16 * K, &Bs[cur ^ 1][ldsOff + q * 512]);
      }
    }
    bf16x8 af[4], bfr[4];
#pragma unroll
    for (int i = 0; i < 4; ++i)
      af[i] = *(const bf16x8*)&As[cur][(64 * wr + 16 * i + lr) * 32 + lc * 8];
#pragma unroll
    for (int j = 0; j < 4; ++j)
      bfr[j] = *(const bf16x8*)&Bs[cur][(64 * wc + 16 * j + lr) * 32 + lc * 8];
#pragma unroll
    for (int i = 0; i < 4; ++i)
#pragma unroll
      for (int j = 0; j < 4; ++j)
        acc[i][j] = __builtin_amdgcn_mfma_f32_16x16x32_bf16(af[i], bfr[j], acc[i][j], 0, 0, 0);
    __syncthreads();
    cur ^= 1;
  }

#pragma unroll
  for (int i = 0; i < 4; ++i)
#pragma unroll
    for (int j = 0; j < 4; ++j) {
      int row = by * 128 + 64 * wr + 16 * i + lc * 4;
      int col = bx * 128 + 64 * wc + 16 * j + lr;
#pragma unroll
      for (int r = 0; r < 4; ++r) {
        if (OUTF32)
          ((float*)C)[(size_t)(row + r) * N + col] = acc[i][j][r];
        else
          ((ushort*)C)[(size_t)(row + r) * N + col] = f2bf(acc[i][j][r]);
      }
    }
}

// ---------------- 256^2 8-phase GEMM (m201 template): C = A * B^T ----------------
template <int OUTF32>
__global__ __launch_bounds__(512, 2) void gemm256_kernel(const ushort* __restrict__ A,
                                                         const ushort* __restrict__ B,
                                                         void* __restrict__ C,
                                                         int M, int N, int K) {
  __shared__ ushort As[2][256 * 64];  // 64 KB
  __shared__ ushort Bs[2][256 * 64];  // 64 KB
  const int tid = threadIdx.x;
  const int w = tid >> 6, l = tid & 63;
  const int lr = l & 15, lc = l >> 4;
  const int wr = w >> 2, wc = w & 3;

  // XCD-chunked swizzle (grid multiple of 8)
  const int nbx = N >> 8;
  const int cpx = gridDim.x >> 3;
  const int sw = (blockIdx.x & 7) * cpx + (blockIdx.x >> 3);
  const int bx = sw % nbx, by = sw / nbx;

  const ushort* Asrc = A + (size_t)(by * 256) * K;
  const ushort* Bsrc = B + (size_t)(bx * 256) * K;

  f32x4 z = {0.f, 0.f, 0.f, 0.f};
  f32x4 acc[8][4];
#pragma unroll
  for (int m = 0; m < 8; ++m)
#pragma unroll
    for (int n = 0; n < 4; ++n) acc[m][n] = z;

  const int NK = K >> 6;

  auto stage = [&](int kt2, int s) {
    if (kt2 >= NK) return;
    const int mat = s >> 1, half = s & 1;
    const ushort* g = mat ? Bsrc : Asrc;
    char* lb = (char*)(mat ? &Bs[kt2 & 1][0] : &As[kt2 & 1][0]) + half * 16384 + w * 1024;
#pragma unroll
    for (int i = 0; i < 2; ++i) {
      int row = half * 128 + i * 64 + w * 8 + (l >> 3);
      int csw = ((l & 7) * 16) ^ ((row & 7) << 4);  // inverse-swizzled source col
      gload16(g + (size_t)row * K + kt2 * 64 + (csw >> 1), lb + i * 8192);
    }
  };

  stage(0, 0); stage(0, 1); stage(0, 2); stage(0, 3);
  stage(1, 0);

  bf16x8 af[4][2], bfr[4][2];
  for (int kt = 0; kt < NK; ++kt) {
    const char* Ab = (const char*)&As[kt & 1][0];
    const char* Bb = (const char*)&Bs[kt & 1][0];
    if (kt + 1 < NK) asm volatile("s_waitcnt vmcnt(2)" ::: "memory");
    else             asm volatile("s_waitcnt vmcnt(0)" ::: "memory");
    asm volatile("s_barrier" ::: "memory");

    // ---- phase A: m0-3 x n0-1 ----
#pragma unroll
    for (int m = 0; m < 4; ++m) {
      int row = wr * 128 + m * 16 + lr;
#pragma unroll
      for (int ks = 0; ks < 2; ++ks)
        af[m][ks] = *(const bf16x8*)(Ab + row * 128 + ((ks * 64 + lc * 16) ^ ((row & 7) << 4)));
    }
#pragma unroll
    for (int n = 0; n < 2; ++n) {
      int row = wc * 64 + n * 16 + lr;
#pragma unroll
      for (int ks = 0; ks < 2; ++ks)
        bfr[n][ks] = *(const bf16x8*)(Bb + row * 128 + ((ks * 64 + lc * 16) ^ ((row & 7) << 4)));
    }
    stage(kt + 1, 1);
    __builtin_amdgcn_s_setprio(1);
#pragma unroll
    for (int m = 0; m < 4; ++m)
#pragma unroll
      for (int n = 0; n < 2; ++n)
#pragma unroll
        for (int ks = 0; ks < 2; ++ks)
          acc[m][n] = __builtin_amdgcn_mfma_f32_16x16x32_bf16(af[m][ks], bfr[n][ks], acc[m][n], 0, 0, 0);
    __builtin_amdgcn_s_setprio(0);
    asm volatile("s_barrier" ::: "memory");

    // ---- phase B: m0-3 x n2-3 ----
#pragma unroll
    for (int n = 2; n < 4; ++n) {
      int row = wc * 64 + n * 16 + lr;
#pragma unroll
      for (int ks = 0; ks < 2; ++ks)
        bfr[n][ks] = *(const bf16x8*)(Bb + row * 128 + ((ks * 64 + lc * 16) ^ ((row & 7) << 4)));
    }
    stage(kt + 1, 2);
    __builtin_amdgcn_s_setprio(1);
#pragma unroll
    for (int m = 0; m < 4; ++m)
#pragma unroll
      for (int n = 2; n < 4; ++n)
#pragma unroll
        for (int ks = 0; ks < 2; ++ks)
          acc[m][n] = __builtin_amdgcn_mfma_f32_16x16x32_bf16(af[m][ks], bfr[n][ks], acc[m][n], 0, 0, 0);
    __builtin_amdgcn_s_setprio(0);
    asm volatile("s_barrier" ::: "memory");

    // ---- phase C: m4-7 x n0-1 ----
#pragma unroll
    for (int m = 0; m < 4; ++m) {
      int row = wr * 128 + (m + 4) * 16 + lr;
#pragma unroll
      for (int ks = 0; ks < 2; ++ks)
        af[m][ks] = *(const bf16x8*)(Ab + row * 128 + ((ks * 64 + lc * 16) ^ ((row & 7) << 4)));
    }
    stage(kt + 1, 3);
    __builtin_amdgcn_s_setprio(1);
#pragma unroll
    for (int m = 0; m < 4; ++m)
#pragma unroll
      for (int n = 0; n < 2; ++n)
#pragma unroll
        for (int ks = 0; ks < 2; ++ks)
          acc[m + 4][n] = __builtin_amdgcn_mfma_f32_16x16x32_bf16(af[m][ks], bfr[n][ks], acc[m + 4][n], 0, 0, 0);
    __builtin_amdgcn_s_setprio(0);
    asm volatile("s_barrier" ::: "memory");

    // ---- phase D: m4-7 x n2-3 ----
    stage(kt + 2, 0);
    __builtin_amdgcn_s_setprio(1);
#pragma unroll
    for (int m = 0; m < 4; ++m)
#pragma unroll
      for (int n = 2; n < 4; ++n)
#pragma unroll
        for (int ks = 0; ks < 2; ++ks)
          acc[m + 4][n] = __builtin_amdgcn_mfma_f32_16x16x32_bf16(af[m][ks], bfr[n][ks], acc[m + 4][n], 0, 0, 0);
    __builtin_amdgcn_s_setprio(0);
  }

#pragma unroll
  for (int m = 0; m < 8; ++m)
#pragma unroll
    for (int n = 0; n < 4; ++n) {
      int row = by * 256 + wr * 128 + m * 16 + lc * 4;
      int col = bx * 256 + wc * 64 + n * 16 + lr;
#pragma unroll
      for (int r = 0; r < 4; ++r) {
        if (OUTF32)
          ((float*)C)[(size_t)(row + r) * N + col] = acc[m][n][r];
        else
          ((ushort*)C)[(size_t)(row + r) * N + col] = f2bf(acc[m][n][r]);
      }
    }
}

// ---------------- RoPE + relayout to [b][h][s][d] ----------------
__global__ __launch_bounds__(256) void rope_kernel(const ushort* __restrict__ in, int ld,
                                                   const float* __restrict__ cosb,
                                                   const float* __restrict__ sinb,
                                                   ushort* __restrict__ out,
                                                   int hshift, float scale) {
  int idx = blockIdx.x * 256 + threadIdx.x;
  int d = idx & 63;
  int nh = 1 << hshift;
  int h = (idx >> 6) & (nh - 1);
  int rowg = idx >> (6 + hshift);  // b*SEQ + s
  int s = rowg & (SEQ - 1);
  int b = rowg >> 11;
  const ushort* p = in + (size_t)rowg * ld + h * HD + d;
  float x = bf2f(p[0]), y = bf2f(p[64]);
  float c = cosb[s * HD + d], sn = sinb[s * HD + d];
  ushort* qo = out + (((size_t)(b * nh + h)) * SEQ + s) * HD + d;
  qo[0] = f2bf((x * c - y * sn) * scale);
  qo[64] = f2bf((y * c + x * sn) * scale);
}

// ---------------- V transpose: kv_lin cols [1024,2048) -> [b][kvh][d][s] ----------------
__global__ __launch_bounds__(256) void vtrans_kernel(const ushort* __restrict__ vin,
                                                     ushort* __restrict__ vout) {
  __shared__ ushort t[64][66];
  const int s0 = blockIdx.x * 64;
  const int c0 = blockIdx.y * 64;  // v-col block, [0,1024)
  const int b = blockIdx.z;
  const int tx = threadIdx.x & 63;
  const int ty = threadIdx.x >> 6;
#pragma unroll
  for (int rr = 0; rr < 64; rr += 4) {
    int r = rr + ty;
    t[r][tx] = vin[((size_t)(b * SEQ + s0 + r)) * 2048 + 1024 + c0 + tx];
  }
  __syncthreads();
#pragma unroll
  for (int rr = 0; rr < 64; rr += 4) {
    int c = rr + ty;
    int cg = c0 + c;
    int kvh = cg >> 7, d = cg & 127;
    vout[(((size_t)(b * NKV + kvh)) * HD + d) * SEQ + s0 + tx] = t[tx][c];
  }
}

// ---------------- Flash attention (causal, GQA), swapped-operand 32x32 ----------------
// 512 blocks x 8 waves; waves 0-3 own q-tile qpi, waves 4-7 own 15-qpi, sharing
// staged tiles. K double-buffered (32KB); V SINGLE-buffered (16KB) with counted
// mid-wait vmcnt(2) + raw s_barrier before PV (K[t+1] stays in flight) ->
// 48KB LDS -> 3 blocks/CU (24 waves). Lane-local log2 softmax; P in regs.
__global__ __launch_bounds__(512, 6) void attn_kernel(const ushort* __restrict__ Qh,
                                                      const ushort* __restrict__ Kh,
                                                      const ushort* __restrict__ Vt,
                                                      ushort* __restrict__ Out) {
  __shared__ ushort Kl[2][64 * 128];  // 32KB: K tile, rows kv (256B), XOR-swz
  __shared__ ushort Vl[128 * 64];     // 16KB: V^T tile, rows d (128B), XOR-swz

  const int tid = threadIdx.x;
  const int w = tid >> 6, l = tid & 63;
  const int lq = l & 31;   // this lane's q column
  const int hl = l >> 5;   // lane half
  const int g = w >> 2;    // q-tile group (0: small, 1: large)
  const int wl = w & 3;    // 32-row slice within the q-tile

  // decode: XCD (n&7) owns (bb,kvh) pairs {2x,2x+1}
  const int n = blockIdx.x;           // [0,512)
  const int xcd = n & 7, i = n >> 3;  // i in [0,64)
  const int qpi = i & 7;
  const int h2 = (i >> 3) & 3;
  const int pp = 2 * xcd + (i >> 5);  // bb*8 + kvh
  const int bb = pp >> 3, kvh = pp & 7;
  const int hh = kvh * 4 + h2;
  const int bh = bb * 32 + hh;
  const int qt = g ? (15 - qpi) : qpi;
  const int q0 = qt * 128;
  const int wrow0 = q0 + 32 * wl;
  const int qrow = wrow0 + lq;

  const ushort* Kbase = Kh + ((size_t)(bb * NKV + kvh) * SEQ) * HD;
  const ushort* Vbase = Vt + ((size_t)(bb * NKV + kvh) * HD) * SEQ;

  // Q fragments (B-operand: col=q=lane&31, k = 8*hl + j per 16-step)
  bf16x8 qf[8];
  {
    const ushort* qrp = Qh + ((size_t)bh * SEQ + qrow) * HD + 8 * hl;
#pragma unroll
    for (int s8 = 0; s8 < 8; ++s8) qf[s8] = *(const bf16x8*)(qrp + 16 * s8);
  }

  f32x16 o[4];
#pragma unroll
  for (int db = 0; db < 4; ++db)
#pragma unroll
    for (int i2 = 0; i2 < 16; ++i2) o[db][i2] = 0.f;
  float m_run = -1e30f, l_run = 0.f;

  const int ntw = 2 * qt + (wl >> 1) + 1;  // this wave's compute-tile count
  const int ntb = 2 * (15 - qpi) + 2;      // block staged-tile count (group B range)

  auto stageK = [&](int buf, int t) {
    const int kv0 = t * 64;
#pragma unroll
    for (int q = 0; q < 2; ++q) {
      int c = 2 * w + q;
      int row = c * 4 + (l >> 4);
      int cs = ((l & 15) ^ (row & 7)) * 8;
      gload16(Kbase + ((size_t)(kv0 + row)) * HD + cs, &Kl[buf][c * 512]);
    }
  };
  auto stageV = [&](int t) {
    const int kv0 = t * 64;
#pragma unroll
    for (int q = 0; q < 2; ++q) {
      int c = 2 * w + q;
      int row = c * 8 + (l >> 3);
      int cs = ((l & 7) ^ (row & 7)) * 8;
      gload16(Vbase + (size_t)row * SEQ + kv0 + cs, &Vl[c * 512]);
    }
  };

  stageK(0, 0);
  __syncthreads();

  int cur = 0;
  for (int t = 0; t < ntb; ++t) {
    const int kv0 = t * 64;
    stageV(t);                            // oldest 2 outstanding loads
    if (t + 1 < ntb) stageK(cur ^ 1, t + 1);

    f32x16 sacc[2];
    unsigned pw[2][8];
    const int swz = lq & 7;
    const bool act = (t < ntw);
    if (act) {
      // S^T = K * Q : C[row=kv][col=q], scores pre-scaled into log2 domain
#pragma unroll
      for (int b2 = 0; b2 < 2; ++b2)
#pragma unroll
        for (int i2 = 0; i2 < 16; ++i2) sacc[b2][i2] = 0.f;

      __builtin_amdgcn_s_setprio(1);
#pragma unroll
      for (int s8 = 0; s8 < 8; ++s8) {
#pragma unroll
        for (int b2 = 0; b2 < 2; ++b2) {
          int row = 32 * b2 + lq;
          bf16x8 kf = *(const bf16x8*)((const char*)&Kl[cur][0] + row * 256 +
                                       (((2 * s8 + hl) ^ swz) << 4));
          sacc[b2] = __builtin_amdgcn_mfma_f32_32x32x16_bf16(kf, qf[s8], sacc[b2], 0, 0, 0);
        }
      }
      __builtin_amdgcn_s_setprio(0);

      if (t == ntw - 1) {  // diagonal tile: causal mask (kv > q)
#pragma unroll
        for (int b2 = 0; b2 < 2; ++b2)
#pragma unroll
          for (int r2 = 0; r2 < 16; ++r2) {
            int kv = kv0 + 32 * b2 + (r2 & 3) + 8 * (r2 >> 2) + 4 * hl;
            if (kv > qrow) sacc[b2][r2] = -1e30f;
          }
      }

      // lane-local softmax, tree-reduced (depth 5)
      float tm[8];
#pragma unroll
      for (int r2 = 0; r2 < 8; ++r2)
        tm[r2] = fmaxf(fmaxf(sacc[0][r2], sacc[0][r2 + 8]),
                       fmaxf(sacc[1][r2], sacc[1][r2 + 8]));
#pragma unroll
      for (int s2 = 4; s2; s2 >>= 1)
#pragma unroll
        for (int r2 = 0; r2 < s2; ++r2) tm[r2] = fmaxf(tm[r2], tm[r2 + s2]);
      float mx = fmaxf(tm[0], __shfl_xor(tm[0], 32));

      if (__any(mx > m_run + 8.0f)) {  // defer-max (T13), log2 domain
        float mn = fmaxf(m_run, mx);
        float sc = exp2_fast(m_run - mn);
        m_run = mn;
        l_run *= sc;
#pragma unroll
        for (int db = 0; db < 4; ++db) o[db] *= sc;
      }

#pragma unroll
      for (int b2 = 0; b2 < 2; ++b2)
#pragma unroll
        for (int r2 = 0; r2 < 16; ++r2) sacc[b2][r2] = exp2_fast(sacc[b2][r2] - m_run);
      float ts[8];
#pragma unroll
      for (int r2 = 0; r2 < 8; ++r2)
        ts[r2] = (sacc[0][r2] + sacc[0][r2 + 8]) + (sacc[1][r2] + sacc[1][r2 + 8]);
#pragma unroll
      for (int s2 = 4; s2; s2 >>= 1)
#pragma unroll
        for (int r2 = 0; r2 < s2; ++r2) ts[r2] += ts[r2 + s2];
      l_run += ts[0] + __shfl_xor(ts[0], 32);

      // pack P to bf16 pairs
#pragma unroll
      for (int b2 = 0; b2 < 2; ++b2)
#pragma unroll
        for (int i2 = 0; i2 < 8; ++i2)
          pw[b2][i2] = cvt_pk_bf16(sacc[b2][2 * i2], sacc[b2][2 * i2 + 1]);
    }

    // mid-wait: V[t]'s 2 per-wave loads are the oldest; K[t+1] (2) may fly on
    if (t + 1 < ntb) asm volatile("s_waitcnt vmcnt(2)" ::: "memory");
    else             asm volatile("s_waitcnt vmcnt(0)" ::: "memory");
    __builtin_amdgcn_s_barrier();
    __builtin_amdgcn_sched_barrier(0);

    if (act) {
      // O^T += V^T * P  (V^T fragments from LDS, swizzled)
#pragma unroll
      for (int s = 0; s < 4; ++s) {
        const int b2 = s >> 1, bs = 4 * (s & 1);
        unsigned wA = pw[b2][bs], wB = pw[b2][bs + 1], wC = pw[b2][bs + 2], wD = pw[b2][bs + 3];
        unsigned s1 = hl ? wA : wC, s2v = hl ? wB : wD;
        unsigned rx1 = (unsigned)__shfl_xor((int)s1, 32);
        unsigned rx2 = (unsigned)__shfl_xor((int)s2v, 32);
        u32x4 fw = {hl ? rx1 : wA, hl ? rx2 : wB, hl ? wC : rx1, hl ? wD : rx2};
        bf16x8 pfrag = __builtin_bit_cast(bf16x8, fw);
        bf16x8 vf[4];
#pragma unroll
        for (int db = 0; db < 4; ++db) {
          int row = 32 * db + lq;
          vf[db] = *(const bf16x8*)((const char*)&Vl[0] + row * 128 +
                                    (((2 * s + hl) ^ swz) << 4));
        }
        __builtin_amdgcn_s_setprio(1);
#pragma unroll
        for (int db = 0; db < 4; ++db)
          o[db] = __builtin_amdgcn_mfma_f32_32x32x16_bf16(vf[db], pfrag, o[db], 0, 0, 0);
        __builtin_amdgcn_s_setprio(0);
      }
    }
    __syncthreads();  // drains vmcnt(0): K[t+1] landed; all Vl reads done
    cur ^= 1;
  }

  // write O^T: lane's column q = qrow; rows d = 32db + (r&3)+8*(r>>2)+4*hl
  const float inv = 1.0f / l_run;
  ushort* outp = Out + ((size_t)bb * SEQ + qrow) * (NH * HD) + hh * HD;
#pragma unroll
  for (int db = 0; db < 4; ++db)
#pragma unroll
    for (int i2 = 0; i2 < 8; ++i2) {
      unsigned wrd = cvt_pk_bf16(o[db][2 * i2] * inv, o[db][2 * i2 + 1] * inv);
      int d = 32 * db + 2 * (i2 & 1) + 8 * (i2 >> 1) + 4 * hl;
      *(unsigned*)(outp + d) = wrd;
    }
}

extern "C" void kernel_launch(void* const* d_in, const int* in_sizes, int n_in,
                              void* d_out, int out_size, void* d_ws, size_t ws_size,
                              hipStream_t stream) {
  const float* hs = (const float*)d_in[0];
  // d_in[1] = attention_mask: exactly causal, applied analytically in attn_kernel
  const float* cosb = (const float*)d_in[2];
  const float* sinb = (const float*)d_in[3];
  const float* wq = (const float*)d_in[4];
  const float* wk = (const float*)d_in[5];
  const float* wv = (const float*)d_in[6];
  const float* wo = (const float*)d_in[7];

  char* ws = (char*)d_ws;
  ushort* hs_bf = (ushort*)(ws);               // 33.5MB [4096][4096]
  ushort* wq_bf = (ushort*)(ws + 33554432);    // 33.5MB
  ushort* wk_bf = (ushort*)(ws + 67108864);    // 8.4MB  (rows 0-1023 of fused wkv)
  ushort* wo_bf = (ushort*)(ws + 83886080);    // 33.5MB
  ushort* q_lin = (ushort*)(ws + 117440512);   // 33.5MB [4096][4096]
  ushort* kv_lin = (ushort*)(ws + 150994944);  // 16.8MB [4096][2048] (K cols 0-1023, V 1024-2047)
  // aliases into regions dead after the projections:
  ushort* Qh = hs_bf;                          // [B][32][S][128]
  ushort* Kh = wq_bf;                          // [B][8][S][128]
  ushort* Vt = (ushort*)(ws + 41943040);       // [B][8][128][S]
  ushort* attn_out = q_lin;                    // [4096][4096]

  // one fused conversion: outputs hs_bf|wq_bf|wk_bf|wv_bf|wo_bf are contiguous
  f2bf5_kernel<<<57344, 256, 0, stream>>>((const float4*)hs, (const float4*)wq,
                                          (const float4*)wk, (const float4*)wv,
                                          (const float4*)wo, (ushort4*)ws);

  gemm256_kernel<0><<<256, 512, 0, stream>>>(hs_bf, wq_bf, q_lin, 4096, 4096, 4096);
  // fused K+V projection: B = [wk;wv] (contiguous), N=2048
  gemm_bt_kernel<0><<<dim3(16, 32), 256, 0, stream>>>(hs_bf, wk_bf, kv_lin, 4096, 2048, 4096);

  // Q pre-scale folds 1/sqrt(128) * log2(e) (softmax runs in log2 domain)
  rope_kernel<<<32768, 256, 0, stream>>>(q_lin, 4096, cosb, sinb, Qh, 5,
                                         0.08838834764831845f * 1.4426950408889634f);
  rope_kernel<<<8192, 256, 0, stream>>>(kv_lin, 2048, cosb, sinb, Kh, 3, 1.0f);
  vtrans_kernel<<<dim3(32, 16, 2), 256, 0, stream>>>(kv_lin, Vt);

  attn_kernel<<<512, 512, 0, stream>>>(Qh, Kh, Vt, attn_out);

  gemm256_kernel<1><<<256, 512, 0, stream>>>(attn_out, wo_bf, d_out, 4096, 4096, 4096);
}

// Round 10
// 533.096 us; speedup vs baseline: 2.3427x; 2.3427x over previous
//
#include <hip/hip_runtime.h>
#include <hip/hip_bf16.h>

typedef __attribute__((ext_vector_type(8))) __bf16 bf16x8;
typedef __attribute__((ext_vector_type(4))) float f32x4;
typedef __attribute__((ext_vector_type(16))) float f32x16;
typedef __attribute__((ext_vector_type(4))) unsigned int u32x4;

#define SEQ 2048
#define NH 32
#define NKV 8
#define HD 128

__device__ __forceinline__ ushort f2bf(float f) {
  unsigned u = __builtin_bit_cast(unsigned, f);
  unsigned r = (u + 0x7fffu + ((u >> 16) & 1u)) >> 16;  // RNE
  return (ushort)r;
}
__device__ __forceinline__ float bf2f(ushort h) {
  return __builtin_bit_cast(float, ((unsigned)h) << 16);
}
__device__ __forceinline__ unsigned cvt_pk_bf16(float lo, float hi) {
  unsigned r;
  asm("v_cvt_pk_bf16_f32 %0, %1, %2" : "=v"(r) : "v"(lo), "v"(hi));
  return r;
}
__device__ __forceinline__ float exp2_fast(float x) {  // scores are in log2 domain
  float r;
  asm("v_exp_f32 %0, %1" : "=v"(r) : "v"(x));
  return r;
}
__device__ __forceinline__ void gload16(const void* g, void* l) {
  __builtin_amdgcn_global_load_lds(
      (const __attribute__((address_space(1))) void*)g,
      (__attribute__((address_space(3))) void*)l, 16, 0, 0);
}

// ---------------- fused f32 -> bf16 convert (all 5 inputs; outputs contiguous) ----------------
__global__ __launch_bounds__(256) void f2bf5_kernel(const float4* __restrict__ hs,
                                                    const float4* __restrict__ wq,
                                                    const float4* __restrict__ wk,
                                                    const float4* __restrict__ wv,
                                                    const float4* __restrict__ wo,
                                                    ushort4* __restrict__ out) {
  unsigned i = blockIdx.x * 256 + threadIdx.x;  // < 14680064
  const float4* src;
  unsigned j;
  if (i < 4194304u) { src = hs; j = i; }
  else if (i < 8388608u) { src = wq; j = i - 4194304u; }
  else if (i < 9437184u) { src = wk; j = i - 8388608u; }
  else if (i < 10485760u) { src = wv; j = i - 9437184u; }
  else { src = wo; j = i - 10485760u; }
  float4 v = src[j];
  ushort4 o;
  o.x = f2bf(v.x); o.y = f2bf(v.y); o.z = f2bf(v.z); o.w = f2bf(v.w);
  out[i] = o;
}

// ---------------- 128^2 GEMM (m97 structure): C = A * B^T ----------------
template <int OUTF32>
__global__ __launch_bounds__(256) void gemm_bt_kernel(const ushort* __restrict__ A,
                                                      const ushort* __restrict__ B,
                                                      void* __restrict__ C,
                                                      int M, int N, int K) {
  __shared__ ushort As[2][128 * 32];
  __shared__ ushort Bs[2][128 * 32];
  const int tid = threadIdx.x;
  const int w = tid >> 6, l = tid & 63;
  const int lr = l & 15, lc = l >> 4;
  const int bx = blockIdx.x, by = blockIdx.y;
  const int wr = w >> 1, wc = w & 1;

  f32x4 z = {0.f, 0.f, 0.f, 0.f};
  f32x4 acc[4][4];
#pragma unroll
  for (int i = 0; i < 4; ++i)
#pragma unroll
    for (int j = 0; j < 4; ++j) acc[i][j] = z;

  const ushort* aSrc = A + (size_t)(by * 128 + 32 * w + (l >> 2)) * K + (l & 3) * 8;
  const ushort* bSrc = B + (size_t)(bx * 128 + 32 * w + (l >> 2)) * K + (l & 3) * 8;
  const int ldsOff = (32 * w) * 32;

#pragma unroll
  for (int q = 0; q < 2; ++q) {
    gload16(aSrc + (size_t)q * 16 * K, &As[0][ldsOff + q * 512]);
    gload16(bSrc + (size_t)q * 16 * K, &Bs[0][ldsOff + q * 512]);
  }
  __syncthreads();

  const int nk = K >> 5;
  int cur = 0;
  for (int kt = 0; kt < nk; ++kt) {
    if (kt + 1 < nk) {
      const ushort* a2 = aSrc + (size_t)(kt + 1) * 32;
      const ushort* b2 = bSrc + (size_t)(kt + 1) * 32;
#pragma unroll
      for (int q = 0; q < 2; ++q) {
        gload16(a2 + (size_t)q * 16 * K, &As[cur ^ 1][ldsOff + q * 512]);
        gload16(b2 + (size_t)q * 16 * K, &Bs[cur ^ 1][ldsOff + q * 512]);
      }
    }
    bf16x8 af[4], bfr[4];
#pragma unroll
    for (int i = 0; i < 4; ++i)
      af[i] = *(const bf16x8*)&As[cur][(64 * wr + 16 * i + lr) * 32 + lc * 8];
#pragma unroll
    for (int j = 0; j < 4; ++j)
      bfr[j] = *(const bf16x8*)&Bs[cur][(64 * wc + 16 * j + lr) * 32 + lc * 8];
#pragma unroll
    for (int i = 0; i < 4; ++i)
#pragma unroll
      for (int j = 0; j < 4; ++j)
        acc[i][j] = __builtin_amdgcn_mfma_f32_16x16x32_bf16(af[i], bfr[j], acc[i][j], 0, 0, 0);
    __syncthreads();
    cur ^= 1;
  }

#pragma unroll
  for (int i = 0; i < 4; ++i)
#pragma unroll
    for (int j = 0; j < 4; ++j) {
      int row = by * 128 + 64 * wr + 16 * i + lc * 4;
      int col = bx * 128 + 64 * wc + 16 * j + lr;
#pragma unroll
      for (int r = 0; r < 4; ++r) {
        if (OUTF32)
          ((float*)C)[(size_t)(row + r) * N + col] = acc[i][j][r];
        else
          ((ushort*)C)[(size_t)(row + r) * N + col] = f2bf(acc[i][j][r]);
      }
    }
}

// ---------------- 256^2 8-phase GEMM (m201 template): C = A * B^T ----------------
template <int OUTF32>
__global__ __launch_bounds__(512, 2) void gemm256_kernel(const ushort* __restrict__ A,
                                                         const ushort* __restrict__ B,
                                                         void* __restrict__ C,
                                                         int M, int N, int K) {
  __shared__ ushort As[2][256 * 64];  // 64 KB
  __shared__ ushort Bs[2][256 * 64];  // 64 KB
  const int tid = threadIdx.x;
  const int w = tid >> 6, l = tid & 63;
  const int lr = l & 15, lc = l >> 4;
  const int wr = w >> 2, wc = w & 3;

  // XCD-chunked swizzle (grid multiple of 8)
  const int nbx = N >> 8;
  const int cpx = gridDim.x >> 3;
  const int sw = (blockIdx.x & 7) * cpx + (blockIdx.x >> 3);
  const int bx = sw % nbx, by = sw / nbx;

  const ushort* Asrc = A + (size_t)(by * 256) * K;
  const ushort* Bsrc = B + (size_t)(bx * 256) * K;

  f32x4 z = {0.f, 0.f, 0.f, 0.f};
  f32x4 acc[8][4];
#pragma unroll
  for (int m = 0; m < 8; ++m)
#pragma unroll
    for (int n = 0; n < 4; ++n) acc[m][n] = z;

  const int NK = K >> 6;

  auto stage = [&](int kt2, int s) {
    if (kt2 >= NK) return;
    const int mat = s >> 1, half = s & 1;
    const ushort* g = mat ? Bsrc : Asrc;
    char* lb = (char*)(mat ? &Bs[kt2 & 1][0] : &As[kt2 & 1][0]) + half * 16384 + w * 1024;
#pragma unroll
    for (int i = 0; i < 2; ++i) {
      int row = half * 128 + i * 64 + w * 8 + (l >> 3);
      int csw = ((l & 7) * 16) ^ ((row & 7) << 4);  // inverse-swizzled source col
      gload16(g + (size_t)row * K + kt2 * 64 + (csw >> 1), lb + i * 8192);
    }
  };

  stage(0, 0); stage(0, 1); stage(0, 2); stage(0, 3);
  stage(1, 0);

  bf16x8 af[4][2], bfr[4][2];
  for (int kt = 0; kt < NK; ++kt) {
    const char* Ab = (const char*)&As[kt & 1][0];
    const char* Bb = (const char*)&Bs[kt & 1][0];
    if (kt + 1 < NK) asm volatile("s_waitcnt vmcnt(2)" ::: "memory");
    else             asm volatile("s_waitcnt vmcnt(0)" ::: "memory");
    asm volatile("s_barrier" ::: "memory");

    // ---- phase A: m0-3 x n0-1 ----
#pragma unroll
    for (int m = 0; m < 4; ++m) {
      int row = wr * 128 + m * 16 + lr;
#pragma unroll
      for (int ks = 0; ks < 2; ++ks)
        af[m][ks] = *(const bf16x8*)(Ab + row * 128 + ((ks * 64 + lc * 16) ^ ((row & 7) << 4)));
    }
#pragma unroll
    for (int n = 0; n < 2; ++n) {
      int row = wc * 64 + n * 16 + lr;
#pragma unroll
      for (int ks = 0; ks < 2; ++ks)
        bfr[n][ks] = *(const bf16x8*)(Bb + row * 128 + ((ks * 64 + lc * 16) ^ ((row & 7) << 4)));
    }
    stage(kt + 1, 1);
    __builtin_amdgcn_s_setprio(1);
#pragma unroll
    for (int m = 0; m < 4; ++m)
#pragma unroll
      for (int n = 0; n < 2; ++n)
#pragma unroll
        for (int ks = 0; ks < 2; ++ks)
          acc[m][n] = __builtin_amdgcn_mfma_f32_16x16x32_bf16(af[m][ks], bfr[n][ks], acc[m][n], 0, 0, 0);
    __builtin_amdgcn_s_setprio(0);
    asm volatile("s_barrier" ::: "memory");

    // ---- phase B: m0-3 x n2-3 ----
#pragma unroll
    for (int n = 2; n < 4; ++n) {
      int row = wc * 64 + n * 16 + lr;
#pragma unroll
      for (int ks = 0; ks < 2; ++ks)
        bfr[n][ks] = *(const bf16x8*)(Bb + row * 128 + ((ks * 64 + lc * 16) ^ ((row & 7) << 4)));
    }
    stage(kt + 1, 2);
    __builtin_amdgcn_s_setprio(1);
#pragma unroll
    for (int m = 0; m < 4; ++m)
#pragma unroll
      for (int n = 2; n < 4; ++n)
#pragma unroll
        for (int ks = 0; ks < 2; ++ks)
          acc[m][n] = __builtin_amdgcn_mfma_f32_16x16x32_bf16(af[m][ks], bfr[n][ks], acc[m][n], 0, 0, 0);
    __builtin_amdgcn_s_setprio(0);
    asm volatile("s_barrier" ::: "memory");

    // ---- phase C: m4-7 x n0-1 ----
#pragma unroll
    for (int m = 0; m < 4; ++m) {
      int row = wr * 128 + (m + 4) * 16 + lr;
#pragma unroll
      for (int ks = 0; ks < 2; ++ks)
        af[m][ks] = *(const bf16x8*)(Ab + row * 128 + ((ks * 64 + lc * 16) ^ ((row & 7) << 4)));
    }
    stage(kt + 1, 3);
    __builtin_amdgcn_s_setprio(1);
#pragma unroll
    for (int m = 0; m < 4; ++m)
#pragma unroll
      for (int n = 0; n < 2; ++n)
#pragma unroll
        for (int ks = 0; ks < 2; ++ks)
          acc[m + 4][n] = __builtin_amdgcn_mfma_f32_16x16x32_bf16(af[m][ks], bfr[n][ks], acc[m + 4][n], 0, 0, 0);
    __builtin_amdgcn_s_setprio(0);
    asm volatile("s_barrier" ::: "memory");

    // ---- phase D: m4-7 x n2-3 ----
    stage(kt + 2, 0);
    __builtin_amdgcn_s_setprio(1);
#pragma unroll
    for (int m = 0; m < 4; ++m)
#pragma unroll
      for (int n = 2; n < 4; ++n)
#pragma unroll
        for (int ks = 0; ks < 2; ++ks)
          acc[m + 4][n] = __builtin_amdgcn_mfma_f32_16x16x32_bf16(af[m][ks], bfr[n][ks], acc[m + 4][n], 0, 0, 0);
    __builtin_amdgcn_s_setprio(0);
  }

#pragma unroll
  for (int m = 0; m < 8; ++m)
#pragma unroll
    for (int n = 0; n < 4; ++n) {
      int row = by * 256 + wr * 128 + m * 16 + lc * 4;
      int col = bx * 256 + wc * 64 + n * 16 + lr;
#pragma unroll
      for (int r = 0; r < 4; ++r) {
        if (OUTF32)
          ((float*)C)[(size_t)(row + r) * N + col] = acc[m][n][r];
        else
          ((ushort*)C)[(size_t)(row + r) * N + col] = f2bf(acc[m][n][r]);
      }
    }
}

// ---------------- RoPE + relayout to [b][h][s][d] ----------------
__global__ __launch_bounds__(256) void rope_kernel(const ushort* __restrict__ in, int ld,
                                                   const float* __restrict__ cosb,
                                                   const float* __restrict__ sinb,
                                                   ushort* __restrict__ out,
                                                   int hshift, float scale) {
  int idx = blockIdx.x * 256 + threadIdx.x;
  int d = idx & 63;
  int nh = 1 << hshift;
  int h = (idx >> 6) & (nh - 1);
  int rowg = idx >> (6 + hshift);  // b*SEQ + s
  int s = rowg & (SEQ - 1);
  int b = rowg >> 11;
  const ushort* p = in + (size_t)rowg * ld + h * HD + d;
  float x = bf2f(p[0]), y = bf2f(p[64]);
  float c = cosb[s * HD + d], sn = sinb[s * HD + d];
  ushort* qo = out + (((size_t)(b * nh + h)) * SEQ + s) * HD + d;
  qo[0] = f2bf((x * c - y * sn) * scale);
  qo[64] = f2bf((y * c + x * sn) * scale);
}

// ---------------- V transpose: kv_lin cols [1024,2048) -> [b][kvh][d][s] ----------------
__global__ __launch_bounds__(256) void vtrans_kernel(const ushort* __restrict__ vin,
                                                     ushort* __restrict__ vout) {
  __shared__ ushort t[64][66];
  const int s0 = blockIdx.x * 64;
  const int c0 = blockIdx.y * 64;  // v-col block, [0,1024)
  const int b = blockIdx.z;
  const int tx = threadIdx.x & 63;
  const int ty = threadIdx.x >> 6;
#pragma unroll
  for (int rr = 0; rr < 64; rr += 4) {
    int r = rr + ty;
    t[r][tx] = vin[((size_t)(b * SEQ + s0 + r)) * 2048 + 1024 + c0 + tx];
  }
  __syncthreads();
#pragma unroll
  for (int rr = 0; rr < 64; rr += 4) {
    int c = rr + ty;
    int cg = c0 + c;
    int kvh = cg >> 7, d = cg & 127;
    vout[(((size_t)(b * NKV + kvh)) * HD + d) * SEQ + s0 + tx] = t[tx][c];
  }
}

// ---------------- Flash attention (causal, GQA), swapped-operand 32x32 ----------------
// 512 blocks x 8 waves; waves 0-3 own q-tile qpi, waves 4-7 own 15-qpi, sharing
// staged tiles. K double-buffered (32KB); V SINGLE-buffered (16KB) with counted
// mid-wait vmcnt(2) + raw s_barrier before PV (K[t+1] stays in flight) ->
// 48KB LDS -> 3 blocks/CU IF natural VGPR <= 85 (was 84 in round 8).
// NOTE: launch_bounds min-waves arg must stay 2 — forcing 6 made the allocator
// collapse to 40 VGPRs and spill (round 9: FETCH 24GB -> 1.35TB, 6x slower).
__global__ __launch_bounds__(512, 2) void attn_kernel(const ushort* __restrict__ Qh,
                                                      const ushort* __restrict__ Kh,
                                                      const ushort* __restrict__ Vt,
                                                      ushort* __restrict__ Out) {
  __shared__ ushort Kl[2][64 * 128];  // 32KB: K tile, rows kv (256B), XOR-swz
  __shared__ ushort Vl[128 * 64];     // 16KB: V^T tile, rows d (128B), XOR-swz

  const int tid = threadIdx.x;
  const int w = tid >> 6, l = tid & 63;
  const int lq = l & 31;   // this lane's q column
  const int hl = l >> 5;   // lane half
  const int g = w >> 2;    // q-tile group (0: small, 1: large)
  const int wl = w & 3;    // 32-row slice within the q-tile

  // decode: XCD (n&7) owns (bb,kvh) pairs {2x,2x+1}
  const int n = blockIdx.x;           // [0,512)
  const int xcd = n & 7, i = n >> 3;  // i in [0,64)
  const int qpi = i & 7;
  const int h2 = (i >> 3) & 3;
  const int pp = 2 * xcd + (i >> 5);  // bb*8 + kvh
  const int bb = pp >> 3, kvh = pp & 7;
  const int hh = kvh * 4 + h2;
  const int bh = bb * 32 + hh;
  const int qt = g ? (15 - qpi) : qpi;
  const int q0 = qt * 128;
  const int wrow0 = q0 + 32 * wl;
  const int qrow = wrow0 + lq;

  const ushort* Kbase = Kh + ((size_t)(bb * NKV + kvh) * SEQ) * HD;
  const ushort* Vbase = Vt + ((size_t)(bb * NKV + kvh) * HD) * SEQ;

  // Q fragments (B-operand: col=q=lane&31, k = 8*hl + j per 16-step)
  bf16x8 qf[8];
  {
    const ushort* qrp = Qh + ((size_t)bh * SEQ + qrow) * HD + 8 * hl;
#pragma unroll
    for (int s8 = 0; s8 < 8; ++s8) qf[s8] = *(const bf16x8*)(qrp + 16 * s8);
  }

  f32x16 o[4];
#pragma unroll
  for (int db = 0; db < 4; ++db)
#pragma unroll
    for (int i2 = 0; i2 < 16; ++i2) o[db][i2] = 0.f;
  float m_run = -1e30f, l_run = 0.f;

  const int ntw = 2 * qt + (wl >> 1) + 1;  // this wave's compute-tile count
  const int ntb = 2 * (15 - qpi) + 2;      // block staged-tile count (group B range)

  auto stageK = [&](int buf, int t) {
    const int kv0 = t * 64;
#pragma unroll
    for (int q = 0; q < 2; ++q) {
      int c = 2 * w + q;
      int row = c * 4 + (l >> 4);
      int cs = ((l & 15) ^ (row & 7)) * 8;
      gload16(Kbase + ((size_t)(kv0 + row)) * HD + cs, &Kl[buf][c * 512]);
    }
  };
  auto stageV = [&](int t) {
    const int kv0 = t * 64;
#pragma unroll
    for (int q = 0; q < 2; ++q) {
      int c = 2 * w + q;
      int row = c * 8 + (l >> 3);
      int cs = ((l & 7) ^ (row & 7)) * 8;
      gload16(Vbase + (size_t)row * SEQ + kv0 + cs, &Vl[c * 512]);
    }
  };

  stageK(0, 0);
  __syncthreads();

  int cur = 0;
  for (int t = 0; t < ntb; ++t) {
    const int kv0 = t * 64;
    stageV(t);                            // oldest 2 outstanding loads
    if (t + 1 < ntb) stageK(cur ^ 1, t + 1);

    f32x16 sacc[2];
    unsigned pw[2][8];
    const int swz = lq & 7;
    const bool act = (t < ntw);
    if (act) {
      // S^T = K * Q : C[row=kv][col=q], scores pre-scaled into log2 domain
#pragma unroll
      for (int b2 = 0; b2 < 2; ++b2)
#pragma unroll
        for (int i2 = 0; i2 < 16; ++i2) sacc[b2][i2] = 0.f;

      __builtin_amdgcn_s_setprio(1);
#pragma unroll
      for (int s8 = 0; s8 < 8; ++s8) {
#pragma unroll
        for (int b2 = 0; b2 < 2; ++b2) {
          int row = 32 * b2 + lq;
          bf16x8 kf = *(const bf16x8*)((const char*)&Kl[cur][0] + row * 256 +
                                       (((2 * s8 + hl) ^ swz) << 4));
          sacc[b2] = __builtin_amdgcn_mfma_f32_32x32x16_bf16(kf, qf[s8], sacc[b2], 0, 0, 0);
        }
      }
      __builtin_amdgcn_s_setprio(0);

      if (t == ntw - 1) {  // diagonal tile: causal mask (kv > q)
#pragma unroll
        for (int b2 = 0; b2 < 2; ++b2)
#pragma unroll
          for (int r2 = 0; r2 < 16; ++r2) {
            int kv = kv0 + 32 * b2 + (r2 & 3) + 8 * (r2 >> 2) + 4 * hl;
            if (kv > qrow) sacc[b2][r2] = -1e30f;
          }
      }

      // lane-local softmax, tree-reduced (depth 5)
      float tm[8];
#pragma unroll
      for (int r2 = 0; r2 < 8; ++r2)
        tm[r2] = fmaxf(fmaxf(sacc[0][r2], sacc[0][r2 + 8]),
                       fmaxf(sacc[1][r2], sacc[1][r2 + 8]));
#pragma unroll
      for (int s2 = 4; s2; s2 >>= 1)
#pragma unroll
        for (int r2 = 0; r2 < s2; ++r2) tm[r2] = fmaxf(tm[r2], tm[r2 + s2]);
      float mx = fmaxf(tm[0], __shfl_xor(tm[0], 32));

      if (__any(mx > m_run + 8.0f)) {  // defer-max (T13), log2 domain
        float mn = fmaxf(m_run, mx);
        float sc = exp2_fast(m_run - mn);
        m_run = mn;
        l_run *= sc;
#pragma unroll
        for (int db = 0; db < 4; ++db) o[db] *= sc;
      }

#pragma unroll
      for (int b2 = 0; b2 < 2; ++b2)
#pragma unroll
        for (int r2 = 0; r2 < 16; ++r2) sacc[b2][r2] = exp2_fast(sacc[b2][r2] - m_run);
      float ts[8];
#pragma unroll
      for (int r2 = 0; r2 < 8; ++r2)
        ts[r2] = (sacc[0][r2] + sacc[0][r2 + 8]) + (sacc[1][r2] + sacc[1][r2 + 8]);
#pragma unroll
      for (int s2 = 4; s2; s2 >>= 1)
#pragma unroll
        for (int r2 = 0; r2 < s2; ++r2) ts[r2] += ts[r2 + s2];
      l_run += ts[0] + __shfl_xor(ts[0], 32);

      // pack P to bf16 pairs
#pragma unroll
      for (int b2 = 0; b2 < 2; ++b2)
#pragma unroll
        for (int i2 = 0; i2 < 8; ++i2)
          pw[b2][i2] = cvt_pk_bf16(sacc[b2][2 * i2], sacc[b2][2 * i2 + 1]);
    }

    // mid-wait: V[t]'s 2 per-wave loads are the oldest; K[t+1] (2) may fly on
    if (t + 1 < ntb) asm volatile("s_waitcnt vmcnt(2)" ::: "memory");
    else             asm volatile("s_waitcnt vmcnt(0)" ::: "memory");
    __builtin_amdgcn_s_barrier();
    __builtin_amdgcn_sched_barrier(0);

    if (act) {
      // O^T += V^T * P  (V^T fragments from LDS, swizzled)
#pragma unroll
      for (int s = 0; s < 4; ++s) {
        const int b2 = s >> 1, bs = 4 * (s & 1);
        unsigned wA = pw[b2][bs], wB = pw[b2][bs + 1], wC = pw[b2][bs + 2], wD = pw[b2][bs + 3];
        unsigned s1 = hl ? wA : wC, s2v = hl ? wB : wD;
        unsigned rx1 = (unsigned)__shfl_xor((int)s1, 32);
        unsigned rx2 = (unsigned)__shfl_xor((int)s2v, 32);
        u32x4 fw = {hl ? rx1 : wA, hl ? rx2 : wB, hl ? wC : rx1, hl ? wD : rx2};
        bf16x8 pfrag = __builtin_bit_cast(bf16x8, fw);
        bf16x8 vf[4];
#pragma unroll
        for (int db = 0; db < 4; ++db) {
          int row = 32 * db + lq;
          vf[db] = *(const bf16x8*)((const char*)&Vl[0] + row * 128 +
                                    (((2 * s + hl) ^ swz) << 4));
        }
        __builtin_amdgcn_s_setprio(1);
#pragma unroll
        for (int db = 0; db < 4; ++db)
          o[db] = __builtin_amdgcn_mfma_f32_32x32x16_bf16(vf[db], pfrag, o[db], 0, 0, 0);
        __builtin_amdgcn_s_setprio(0);
      }
    }
    __syncthreads();  // drains vmcnt(0): K[t+1] landed; all Vl reads done
    cur ^= 1;
  }

  // write O^T: lane's column q = qrow; rows d = 32db + (r&3)+8*(r>>2)+4*hl
  const float inv = 1.0f / l_run;
  ushort* outp = Out + ((size_t)bb * SEQ + qrow) * (NH * HD) + hh * HD;
#pragma unroll
  for (int db = 0; db < 4; ++db)
#pragma unroll
    for (int i2 = 0; i2 < 8; ++i2) {
      unsigned wrd = cvt_pk_bf16(o[db][2 * i2] * inv, o[db][2 * i2 + 1] * inv);
      int d = 32 * db + 2 * (i2 & 1) + 8 * (i2 >> 1) + 4 * hl;
      *(unsigned*)(outp + d) = wrd;
    }
}

extern "C" void kernel_launch(void* const* d_in, const int* in_sizes, int n_in,
                              void* d_out, int out_size, void* d_ws, size_t ws_size,
                              hipStream_t stream) {
  const float* hs = (const float*)d_in[0];
  // d_in[1] = attention_mask: exactly causal, applied analytically in attn_kernel
  const float* cosb = (const float*)d_in[2];
  const float* sinb = (const float*)d_in[3];
  const float* wq = (const float*)d_in[4];
  const float* wk = (const float*)d_in[5];
  const float* wv = (const float*)d_in[6];
  const float* wo = (const float*)d_in[7];

  char* ws = (char*)d_ws;
  ushort* hs_bf = (ushort*)(ws);               // 33.5MB [4096][4096]
  ushort* wq_bf = (ushort*)(ws + 33554432);    // 33.5MB
  ushort* wk_bf = (ushort*)(ws + 67108864);    // 8.4MB  (rows 0-1023 of fused wkv)
  ushort* wo_bf = (ushort*)(ws + 83886080);    // 33.5MB
  ushort* q_lin = (ushort*)(ws + 117440512);   // 33.5MB [4096][4096]
  ushort* kv_lin = (ushort*)(ws + 150994944);  // 16.8MB [4096][2048] (K cols 0-1023, V 1024-2047)
  // aliases into regions dead after the projections:
  ushort* Qh = hs_bf;                          // [B][32][S][128]
  ushort* Kh = wq_bf;                          // [B][8][S][128]
  ushort* Vt = (ushort*)(ws + 41943040);       // [B][8][128][S]
  ushort* attn_out = q_lin;                    // [4096][4096]

  // one fused conversion: outputs hs_bf|wq_bf|wk_bf|wv_bf|wo_bf are contiguous
  f2bf5_kernel<<<57344, 256, 0, stream>>>((const float4*)hs, (const float4*)wq,
                                          (const float4*)wk, (const float4*)wv,
                                          (const float4*)wo, (ushort4*)ws);

  gemm256_kernel<0><<<256, 512, 0, stream>>>(hs_bf, wq_bf, q_lin, 4096, 4096, 4096);
  // fused K+V projection: B = [wk;wv] (contiguous), N=2048
  gemm_bt_kernel<0><<<dim3(16, 32), 256, 0, stream>>>(hs_bf, wk_bf, kv_lin, 4096, 2048, 4096);

  // Q pre-scale folds 1/sqrt(128) * log2(e) (softmax runs in log2 domain)
  rope_kernel<<<32768, 256, 0, stream>>>(q_lin, 4096, cosb, sinb, Qh, 5,
                                         0.08838834764831845f * 1.4426950408889634f);
  rope_kernel<<<8192, 256, 0, stream>>>(kv_lin, 2048, cosb, sinb, Kh, 3, 1.0f);
  vtrans_kernel<<<dim3(32, 16, 2), 256, 0, stream>>>(kv_lin, Vt);

  attn_kernel<<<512, 512, 0, stream>>>(Qh, Kh, Vt, attn_out);

  gemm256_kernel<1><<<256, 512, 0, stream>>>(attn_out, wo_bf, d_out, 4096, 4096, 4096);
}

// Round 11
// 524.240 us; speedup vs baseline: 2.3823x; 1.0169x over previous
//
#include <hip/hip_runtime.h>
#include <hip/hip_bf16.h>

typedef __attribute__((ext_vector_type(8))) __bf16 bf16x8;
typedef __attribute__((ext_vector_type(4))) float f32x4;
typedef __attribute__((ext_vector_type(16))) float f32x16;
typedef __attribute__((ext_vector_type(4))) unsigned int u32x4;

#define SEQ 2048
#define NH 32
#define NKV 8
#define HD 128

__device__ __forceinline__ ushort f2bf(float f) {
  unsigned u = __builtin_bit_cast(unsigned, f);
  unsigned r = (u + 0x7fffu + ((u >> 16) & 1u)) >> 16;  // RNE
  return (ushort)r;
}
__device__ __forceinline__ float bf2f(ushort h) {
  return __builtin_bit_cast(float, ((unsigned)h) << 16);
}
__device__ __forceinline__ unsigned cvt_pk_bf16(float lo, float hi) {
  unsigned r;
  asm("v_cvt_pk_bf16_f32 %0, %1, %2" : "=v"(r) : "v"(lo), "v"(hi));
  return r;
}
__device__ __forceinline__ float exp2_fast(float x) {  // scores are in log2 domain
  float r;
  asm("v_exp_f32 %0, %1" : "=v"(r) : "v"(x));
  return r;
}
__device__ __forceinline__ void gload16(const void* g, void* l) {
  __builtin_amdgcn_global_load_lds(
      (const __attribute__((address_space(1))) void*)g,
      (__attribute__((address_space(3))) void*)l, 16, 0, 0);
}

// ---------------- fused f32 -> bf16 convert (all 5 inputs; outputs contiguous) ----------------
__global__ __launch_bounds__(256) void f2bf5_kernel(const float4* __restrict__ hs,
                                                    const float4* __restrict__ wq,
                                                    const float4* __restrict__ wk,
                                                    const float4* __restrict__ wv,
                                                    const float4* __restrict__ wo,
                                                    ushort4* __restrict__ out) {
  unsigned i = blockIdx.x * 256 + threadIdx.x;  // < 14680064
  const float4* src;
  unsigned j;
  if (i < 4194304u) { src = hs; j = i; }
  else if (i < 8388608u) { src = wq; j = i - 4194304u; }
  else if (i < 9437184u) { src = wk; j = i - 8388608u; }
  else if (i < 10485760u) { src = wv; j = i - 9437184u; }
  else { src = wo; j = i - 10485760u; }
  float4 v = src[j];
  ushort4 o;
  o.x = f2bf(v.x); o.y = f2bf(v.y); o.z = f2bf(v.z); o.w = f2bf(v.w);
  out[i] = o;
}

// ---------------- 128^2 GEMM (m97 structure): C = A * B^T ----------------
template <int OUTF32>
__global__ __launch_bounds__(256) void gemm_bt_kernel(const ushort* __restrict__ A,
                                                      const ushort* __restrict__ B,
                                                      void* __restrict__ C,
                                                      int M, int N, int K) {
  __shared__ ushort As[2][128 * 32];
  __shared__ ushort Bs[2][128 * 32];
  const int tid = threadIdx.x;
  const int w = tid >> 6, l = tid & 63;
  const int lr = l & 15, lc = l >> 4;
  const int bx = blockIdx.x, by = blockIdx.y;
  const int wr = w >> 1, wc = w & 1;

  f32x4 z = {0.f, 0.f, 0.f, 0.f};
  f32x4 acc[4][4];
#pragma unroll
  for (int i = 0; i < 4; ++i)
#pragma unroll
    for (int j = 0; j < 4; ++j) acc[i][j] = z;

  const ushort* aSrc = A + (size_t)(by * 128 + 32 * w + (l >> 2)) * K + (l & 3) * 8;
  const ushort* bSrc = B + (size_t)(bx * 128 + 32 * w + (l >> 2)) * K + (l & 3) * 8;
  const int ldsOff = (32 * w) * 32;

#pragma unroll
  for (int q = 0; q < 2; ++q) {
    gload16(aSrc + (size_t)q * 16 * K, &As[0][ldsOff + q * 512]);
    gload16(bSrc + (size_t)q * 16 * K, &Bs[0][ldsOff + q * 512]);
  }
  __syncthreads();

  const int nk = K >> 5;
  int cur = 0;
  for (int kt = 0; kt < nk; ++kt) {
    if (kt + 1 < nk) {
      const ushort* a2 = aSrc + (size_t)(kt + 1) * 32;
      const ushort* b2 = bSrc + (size_t)(kt + 1) * 32;
#pragma unroll
      for (int q = 0; q < 2; ++q) {
        gload16(a2 + (size_t)q * 16 * K, &As[cur ^ 1][ldsOff + q * 512]);
        gload16(b2 + (size_t)q * 16 * K, &Bs[cur ^ 1][ldsOff + q * 512]);
      }
    }
    bf16x8 af[4], bfr[4];
#pragma unroll
    for (int i = 0; i < 4; ++i)
      af[i] = *(const bf16x8*)&As[cur][(64 * wr + 16 * i + lr) * 32 + lc * 8];
#pragma unroll
    for (int j = 0; j < 4; ++j)
      bfr[j] = *(const bf16x8*)&Bs[cur][(64 * wc + 16 * j + lr) * 32 + lc * 8];
#pragma unroll
    for (int i = 0; i < 4; ++i)
#pragma unroll
      for (int j = 0; j < 4; ++j)
        acc[i][j] = __builtin_amdgcn_mfma_f32_16x16x32_bf16(af[i], bfr[j], acc[i][j], 0, 0, 0);
    __syncthreads();
    cur ^= 1;
  }

#pragma unroll
  for (int i = 0; i < 4; ++i)
#pragma unroll
    for (int j = 0; j < 4; ++j) {
      int row = by * 128 + 64 * wr + 16 * i + lc * 4;
      int col = bx * 128 + 64 * wc + 16 * j + lr;
#pragma unroll
      for (int r = 0; r < 4; ++r) {
        if (OUTF32)
          ((float*)C)[(size_t)(row + r) * N + col] = acc[i][j][r];
        else
          ((ushort*)C)[(size_t)(row + r) * N + col] = f2bf(acc[i][j][r]);
      }
    }
}

// ---------------- 256^2 8-phase GEMM (m201 template): C = A * B^T ----------------
template <int OUTF32>
__global__ __launch_bounds__(512, 2) void gemm256_kernel(const ushort* __restrict__ A,
                                                         const ushort* __restrict__ B,
                                                         void* __restrict__ C,
                                                         int M, int N, int K) {
  __shared__ ushort As[2][256 * 64];  // 64 KB
  __shared__ ushort Bs[2][256 * 64];  // 64 KB
  const int tid = threadIdx.x;
  const int w = tid >> 6, l = tid & 63;
  const int lr = l & 15, lc = l >> 4;
  const int wr = w >> 2, wc = w & 3;

  // XCD-chunked swizzle (grid multiple of 8)
  const int nbx = N >> 8;
  const int cpx = gridDim.x >> 3;
  const int sw = (blockIdx.x & 7) * cpx + (blockIdx.x >> 3);
  const int bx = sw % nbx, by = sw / nbx;

  const ushort* Asrc = A + (size_t)(by * 256) * K;
  const ushort* Bsrc = B + (size_t)(bx * 256) * K;

  f32x4 z = {0.f, 0.f, 0.f, 0.f};
  f32x4 acc[8][4];
#pragma unroll
  for (int m = 0; m < 8; ++m)
#pragma unroll
    for (int n = 0; n < 4; ++n) acc[m][n] = z;

  const int NK = K >> 6;

  auto stage = [&](int kt2, int s) {
    if (kt2 >= NK) return;
    const int mat = s >> 1, half = s & 1;
    const ushort* g = mat ? Bsrc : Asrc;
    char* lb = (char*)(mat ? &Bs[kt2 & 1][0] : &As[kt2 & 1][0]) + half * 16384 + w * 1024;
#pragma unroll
    for (int i = 0; i < 2; ++i) {
      int row = half * 128 + i * 64 + w * 8 + (l >> 3);
      int csw = ((l & 7) * 16) ^ ((row & 7) << 4);  // inverse-swizzled source col
      gload16(g + (size_t)row * K + kt2 * 64 + (csw >> 1), lb + i * 8192);
    }
  };

  stage(0, 0); stage(0, 1); stage(0, 2); stage(0, 3);
  stage(1, 0);

  bf16x8 af[4][2], bfr[4][2];
  for (int kt = 0; kt < NK; ++kt) {
    const char* Ab = (const char*)&As[kt & 1][0];
    const char* Bb = (const char*)&Bs[kt & 1][0];
    if (kt + 1 < NK) asm volatile("s_waitcnt vmcnt(2)" ::: "memory");
    else             asm volatile("s_waitcnt vmcnt(0)" ::: "memory");
    asm volatile("s_barrier" ::: "memory");

    // ---- phase A: m0-3 x n0-1 ----
#pragma unroll
    for (int m = 0; m < 4; ++m) {
      int row = wr * 128 + m * 16 + lr;
#pragma unroll
      for (int ks = 0; ks < 2; ++ks)
        af[m][ks] = *(const bf16x8*)(Ab + row * 128 + ((ks * 64 + lc * 16) ^ ((row & 7) << 4)));
    }
#pragma unroll
    for (int n = 0; n < 2; ++n) {
      int row = wc * 64 + n * 16 + lr;
#pragma unroll
      for (int ks = 0; ks < 2; ++ks)
        bfr[n][ks] = *(const bf16x8*)(Bb + row * 128 + ((ks * 64 + lc * 16) ^ ((row & 7) << 4)));
    }
    stage(kt + 1, 1);
    __builtin_amdgcn_s_setprio(1);
#pragma unroll
    for (int m = 0; m < 4; ++m)
#pragma unroll
      for (int n = 0; n < 2; ++n)
#pragma unroll
        for (int ks = 0; ks < 2; ++ks)
          acc[m][n] = __builtin_amdgcn_mfma_f32_16x16x32_bf16(af[m][ks], bfr[n][ks], acc[m][n], 0, 0, 0);
    __builtin_amdgcn_s_setprio(0);
    asm volatile("s_barrier" ::: "memory");

    // ---- phase B: m0-3 x n2-3 ----
#pragma unroll
    for (int n = 2; n < 4; ++n) {
      int row = wc * 64 + n * 16 + lr;
#pragma unroll
      for (int ks = 0; ks < 2; ++ks)
        bfr[n][ks] = *(const bf16x8*)(Bb + row * 128 + ((ks * 64 + lc * 16) ^ ((row & 7) << 4)));
    }
    stage(kt + 1, 2);
    __builtin_amdgcn_s_setprio(1);
#pragma unroll
    for (int m = 0; m < 4; ++m)
#pragma unroll
      for (int n = 2; n < 4; ++n)
#pragma unroll
        for (int ks = 0; ks < 2; ++ks)
          acc[m][n] = __builtin_amdgcn_mfma_f32_16x16x32_bf16(af[m][ks], bfr[n][ks], acc[m][n], 0, 0, 0);
    __builtin_amdgcn_s_setprio(0);
    asm volatile("s_barrier" ::: "memory");

    // ---- phase C: m4-7 x n0-1 ----
#pragma unroll
    for (int m = 0; m < 4; ++m) {
      int row = wr * 128 + (m + 4) * 16 + lr;
#pragma unroll
      for (int ks = 0; ks < 2; ++ks)
        af[m][ks] = *(const bf16x8*)(Ab + row * 128 + ((ks * 64 + lc * 16) ^ ((row & 7) << 4)));
    }
    stage(kt + 1, 3);
    __builtin_amdgcn_s_setprio(1);
#pragma unroll
    for (int m = 0; m < 4; ++m)
#pragma unroll
      for (int n = 0; n < 2; ++n)
#pragma unroll
        for (int ks = 0; ks < 2; ++ks)
          acc[m + 4][n] = __builtin_amdgcn_mfma_f32_16x16x32_bf16(af[m][ks], bfr[n][ks], acc[m + 4][n], 0, 0, 0);
    __builtin_amdgcn_s_setprio(0);
    asm volatile("s_barrier" ::: "memory");

    // ---- phase D: m4-7 x n2-3 ----
    stage(kt + 2, 0);
    __builtin_amdgcn_s_setprio(1);
#pragma unroll
    for (int m = 0; m < 4; ++m)
#pragma unroll
      for (int n = 2; n < 4; ++n)
#pragma unroll
        for (int ks = 0; ks < 2; ++ks)
          acc[m + 4][n] = __builtin_amdgcn_mfma_f32_16x16x32_bf16(af[m][ks], bfr[n][ks], acc[m + 4][n], 0, 0, 0);
    __builtin_amdgcn_s_setprio(0);
  }

#pragma unroll
  for (int m = 0; m < 8; ++m)
#pragma unroll
    for (int n = 0; n < 4; ++n) {
      int row = by * 256 + wr * 128 + m * 16 + lc * 4;
      int col = bx * 256 + wc * 64 + n * 16 + lr;
#pragma unroll
      for (int r = 0; r < 4; ++r) {
        if (OUTF32)
          ((float*)C)[(size_t)(row + r) * N + col] = acc[m][n][r];
        else
          ((ushort*)C)[(size_t)(row + r) * N + col] = f2bf(acc[m][n][r]);
      }
    }
}

// ---------------- merged relayout: rope-Q | rope-K | V-transpose (one dispatch) ----------------
// blocks [0,32768): rope-Q   q_lin[4096][4096] -> Qh[b][32][s][128] (scaled)
// blocks [32768,40960): rope-K  kv_lin[.][0:1024] -> Kh[b][8][s][128]
// blocks [40960,41984): vtrans  kv_lin[.][1024:2048] -> Vt[b][8][128][s]
__global__ __launch_bounds__(256) void relayout_kernel(const ushort* __restrict__ q_lin,
                                                       const ushort* __restrict__ kv_lin,
                                                       const float* __restrict__ cosb,
                                                       const float* __restrict__ sinb,
                                                       ushort* __restrict__ Qh,
                                                       ushort* __restrict__ Kh,
                                                       ushort* __restrict__ Vt,
                                                       float qscale) {
  __shared__ ushort t[64][66];
  const unsigned bid = blockIdx.x;
  if (bid < 40960u) {
    // RoPE path
    const bool isQ = bid < 32768u;
    const ushort* in = isQ ? q_lin : kv_lin;
    ushort* out = isQ ? Qh : Kh;
    const int ld = isQ ? 4096 : 2048;
    const int hshift = isQ ? 5 : 3;
    const float scale = isQ ? qscale : 1.0f;
    int idx = (isQ ? bid : (bid - 32768u)) * 256 + threadIdx.x;
    int d = idx & 63;
    int nh = 1 << hshift;
    int h = (idx >> 6) & (nh - 1);
    int rowg = idx >> (6 + hshift);  // b*SEQ + s
    int s = rowg & (SEQ - 1);
    int b = rowg >> 11;
    const ushort* p = in + (size_t)rowg * ld + h * HD + d;
    float x = bf2f(p[0]), y = bf2f(p[64]);
    float c = cosb[s * HD + d], sn = sinb[s * HD + d];
    ushort* qo = out + (((size_t)(b * nh + h)) * SEQ + s) * HD + d;
    qo[0] = f2bf((x * c - y * sn) * scale);
    qo[64] = f2bf((y * c + x * sn) * scale);
  } else {
    // vtrans path
    unsigned i = bid - 40960u;          // [0,1024)
    const int s0 = (i & 31) * 64;
    const int c0 = ((i >> 5) & 15) * 64;
    const int b = i >> 9;
    const int tx = threadIdx.x & 63;
    const int ty = threadIdx.x >> 6;
#pragma unroll
    for (int rr = 0; rr < 64; rr += 4) {
      int r = rr + ty;
      t[r][tx] = kv_lin[((size_t)(b * SEQ + s0 + r)) * 2048 + 1024 + c0 + tx];
    }
    __syncthreads();
#pragma unroll
    for (int rr = 0; rr < 64; rr += 4) {
      int c = rr + ty;
      int cg = c0 + c;
      int kvh = cg >> 7, d = cg & 127;
      Vt[(((size_t)(b * NKV + kvh)) * HD + d) * SEQ + s0 + tx] = t[tx][c];
    }
  }
}

// ---------------- Flash attention (round-8 proven variant) ----------------
// 512 blocks x 8 waves; waves 0-3 own q-tile qpi, waves 4-7 own 15-qpi, sharing
// staged K/V tiles (A's causal range is a prefix of B's); each SIMD hosts one
// wave of each group -> per-SIMD work uniform. K and V^T both LDS-staged
// (dbuf, XOR-swizzled). Lane-local log2 softmax; P in registers.
// NOTE: do NOT raise the 2nd launch_bounds arg — forcing 4 (r6) or 6 (r9)
// collapses VGPRs (64/40) and spills catastrophically. Natural VGPR = 84.
__global__ __launch_bounds__(512, 2) void attn_kernel(const ushort* __restrict__ Qh,
                                                      const ushort* __restrict__ Kh,
                                                      const ushort* __restrict__ Vt,
                                                      ushort* __restrict__ Out) {
  __shared__ ushort Kl[2][64 * 128];   // 32KB: K tile, rows kv (256B), XOR-swz
  __shared__ ushort Vl[2][128 * 64];   // 32KB: V^T tile, rows d (128B), XOR-swz

  const int tid = threadIdx.x;
  const int w = tid >> 6, l = tid & 63;
  const int lq = l & 31;   // this lane's q column
  const int hl = l >> 5;   // lane half
  const int g = w >> 2;    // q-tile group (0: small, 1: large)
  const int wl = w & 3;    // 32-row slice within the q-tile

  // decode: XCD (n&7) owns (bb,kvh) pairs {2x,2x+1}
  const int n = blockIdx.x;           // [0,512)
  const int xcd = n & 7, i = n >> 3;  // i in [0,64)
  const int qpi = i & 7;
  const int h2 = (i >> 3) & 3;
  const int pp = 2 * xcd + (i >> 5);  // bb*8 + kvh
  const int bb = pp >> 3, kvh = pp & 7;
  const int hh = kvh * 4 + h2;
  const int bh = bb * 32 + hh;
  const int qt = g ? (15 - qpi) : qpi;
  const int q0 = qt * 128;
  const int wrow0 = q0 + 32 * wl;
  const int qrow = wrow0 + lq;

  const ushort* Kbase = Kh + ((size_t)(bb * NKV + kvh) * SEQ) * HD;
  const ushort* Vbase = Vt + ((size_t)(bb * NKV + kvh) * HD) * SEQ;

  // Q fragments (B-operand: col=q=lane&31, k = 8*hl + j per 16-step)
  bf16x8 qf[8];
  {
    const ushort* qrp = Qh + ((size_t)bh * SEQ + qrow) * HD + 8 * hl;
#pragma unroll
    for (int s8 = 0; s8 < 8; ++s8) qf[s8] = *(const bf16x8*)(qrp + 16 * s8);
  }

  f32x16 o[4];
#pragma unroll
  for (int db = 0; db < 4; ++db)
#pragma unroll
    for (int i2 = 0; i2 < 16; ++i2) o[db][i2] = 0.f;
  float m_run = -1e30f, l_run = 0.f;

  const int ntw = 2 * qt + (wl >> 1) + 1;  // this wave's compute-tile count
  const int ntb = 2 * (15 - qpi) + 2;      // block staged-tile count (group B range)

  // stage K (16 chunks x 1KB: 4 rows of 256B) + V^T (16 chunks x 1KB: 8 rows
  // of 128B); wave w handles chunks {2w, 2w+1} of each.
  auto stageKV = [&](int buf, int t) {
    const int kv0 = t * 64;
#pragma unroll
    for (int q = 0; q < 2; ++q) {
      int c = 2 * w + q;
      int row = c * 4 + (l >> 4);
      int cs = ((l & 15) ^ (row & 7)) * 8;
      gload16(Kbase + ((size_t)(kv0 + row)) * HD + cs, &Kl[buf][c * 512]);
    }
#pragma unroll
    for (int q = 0; q < 2; ++q) {
      int c = 2 * w + q;
      int row = c * 8 + (l >> 3);
      int cs = ((l & 7) ^ (row & 7)) * 8;
      gload16(Vbase + (size_t)row * SEQ + kv0 + cs, &Vl[buf][c * 512]);
    }
  };

  stageKV(0, 0);
  __syncthreads();

  int cur = 0;
  for (int t = 0; t < ntb; ++t) {
    const int kv0 = t * 64;
    if (t + 1 < ntb) stageKV(cur ^ 1, t + 1);

    if (t < ntw) {
      // S^T = K * Q : C[row=kv][col=q], scores pre-scaled into log2 domain
      f32x16 sacc[2];
#pragma unroll
      for (int b2 = 0; b2 < 2; ++b2)
#pragma unroll
        for (int i2 = 0; i2 < 16; ++i2) sacc[b2][i2] = 0.f;

      const int swz = lq & 7;
      __builtin_amdgcn_s_setprio(1);
#pragma unroll
      for (int s8 = 0; s8 < 8; ++s8) {
#pragma unroll
        for (int b2 = 0; b2 < 2; ++b2) {
          int row = 32 * b2 + lq;
          bf16x8 kf = *(const bf16x8*)((const char*)&Kl[cur][0] + row * 256 +
                                       (((2 * s8 + hl) ^ swz) << 4));
          sacc[b2] = __builtin_amdgcn_mfma_f32_32x32x16_bf16(kf, qf[s8], sacc[b2], 0, 0, 0);
        }
      }
      __builtin_amdgcn_s_setprio(0);

      if (t == ntw - 1) {  // diagonal tile: causal mask (kv > q)
#pragma unroll
        for (int b2 = 0; b2 < 2; ++b2)
#pragma unroll
          for (int r2 = 0; r2 < 16; ++r2) {
            int kv = kv0 + 32 * b2 + (r2 & 3) + 8 * (r2 >> 2) + 4 * hl;
            if (kv > qrow) sacc[b2][r2] = -1e30f;
          }
      }

      // lane-local softmax, tree-reduced (depth 5)
      float tm[8];
#pragma unroll
      for (int r2 = 0; r2 < 8; ++r2)
        tm[r2] = fmaxf(fmaxf(sacc[0][r2], sacc[0][r2 + 8]),
                       fmaxf(sacc[1][r2], sacc[1][r2 + 8]));
#pragma unroll
      for (int s2 = 4; s2; s2 >>= 1)
#pragma unroll
        for (int r2 = 0; r2 < s2; ++r2) tm[r2] = fmaxf(tm[r2], tm[r2 + s2]);
      float mx = fmaxf(tm[0], __shfl_xor(tm[0], 32));

      if (__any(mx > m_run + 8.0f)) {  // defer-max (T13), log2 domain
        float mn = fmaxf(m_run, mx);
        float sc = exp2_fast(m_run - mn);
        m_run = mn;
        l_run *= sc;
#pragma unroll
        for (int db = 0; db < 4; ++db) o[db] *= sc;
      }

#pragma unroll
      for (int b2 = 0; b2 < 2; ++b2)
#pragma unroll
        for (int r2 = 0; r2 < 16; ++r2) sacc[b2][r2] = exp2_fast(sacc[b2][r2] - m_run);
      float ts[8];
#pragma unroll
      for (int r2 = 0; r2 < 8; ++r2)
        ts[r2] = (sacc[0][r2] + sacc[0][r2 + 8]) + (sacc[1][r2] + sacc[1][r2 + 8]);
#pragma unroll
      for (int s2 = 4; s2; s2 >>= 1)
#pragma unroll
        for (int r2 = 0; r2 < s2; ++r2) ts[r2] += ts[r2 + s2];
      l_run += ts[0] + __shfl_xor(ts[0], 32);

      // pack P to bf16 pairs
      unsigned pw[2][8];
#pragma unroll
      for (int b2 = 0; b2 < 2; ++b2)
#pragma unroll
        for (int i2 = 0; i2 < 8; ++i2)
          pw[b2][i2] = cvt_pk_bf16(sacc[b2][2 * i2], sacc[b2][2 * i2 + 1]);

      // O^T += V^T * P  (V^T fragments from LDS, swizzled)
#pragma unroll
      for (int s = 0; s < 4; ++s) {
        const int b2 = s >> 1, bs = 4 * (s & 1);
        unsigned wA = pw[b2][bs], wB = pw[b2][bs + 1], wC = pw[b2][bs + 2], wD = pw[b2][bs + 3];
        unsigned s1 = hl ? wA : wC, s2v = hl ? wB : wD;
        unsigned rx1 = (unsigned)__shfl_xor((int)s1, 32);
        unsigned rx2 = (unsigned)__shfl_xor((int)s2v, 32);
        u32x4 fw = {hl ? rx1 : wA, hl ? rx2 : wB, hl ? wC : rx1, hl ? wD : rx2};
        bf16x8 pfrag = __builtin_bit_cast(bf16x8, fw);
        bf16x8 vf[4];
#pragma unroll
        for (int db = 0; db < 4; ++db) {
          int row = 32 * db + lq;
          vf[db] = *(const bf16x8*)((const char*)&Vl[cur][0] + row * 128 +
                                    (((2 * s + hl) ^ swz) << 4));
        }
        __builtin_amdgcn_s_setprio(1);
#pragma unroll
        for (int db = 0; db < 4; ++db)
          o[db] = __builtin_amdgcn_mfma_f32_32x32x16_bf16(vf[db], pfrag, o[db], 0, 0, 0);
        __builtin_amdgcn_s_setprio(0);
      }
    }
    __syncthreads();
    cur ^= 1;
  }

  // write O^T: lane's column q = qrow; rows d = 32db + (r&3)+8*(r>>2)+4*hl
  const float inv = 1.0f / l_run;
  ushort* outp = Out + ((size_t)bb * SEQ + qrow) * (NH * HD) + hh * HD;
#pragma unroll
  for (int db = 0; db < 4; ++db)
#pragma unroll
    for (int i2 = 0; i2 < 8; ++i2) {
      unsigned wrd = cvt_pk_bf16(o[db][2 * i2] * inv, o[db][2 * i2 + 1] * inv);
      int d = 32 * db + 2 * (i2 & 1) + 8 * (i2 >> 1) + 4 * hl;
      *(unsigned*)(outp + d) = wrd;
    }
}

extern "C" void kernel_launch(void* const* d_in, const int* in_sizes, int n_in,
                              void* d_out, int out_size, void* d_ws, size_t ws_size,
                              hipStream_t stream) {
  const float* hs = (const float*)d_in[0];
  // d_in[1] = attention_mask: exactly causal, applied analytically in attn_kernel
  const float* cosb = (const float*)d_in[2];
  const float* sinb = (const float*)d_in[3];
  const float* wq = (const float*)d_in[4];
  const float* wk = (const float*)d_in[5];
  const float* wv = (const float*)d_in[6];
  const float* wo = (const float*)d_in[7];

  char* ws = (char*)d_ws;
  ushort* hs_bf = (ushort*)(ws);               // 33.5MB [4096][4096]
  ushort* wq_bf = (ushort*)(ws + 33554432);    // 33.5MB
  ushort* wk_bf = (ushort*)(ws + 67108864);    // 8.4MB  (rows 0-1023 of fused wkv)
  ushort* wo_bf = (ushort*)(ws + 83886080);    // 33.5MB
  ushort* q_lin = (ushort*)(ws + 117440512);   // 33.5MB [4096][4096]
  ushort* kv_lin = (ushort*)(ws + 150994944);  // 16.8MB [4096][2048] (K cols 0-1023, V 1024-2047)
  // aliases into regions dead after the projections:
  ushort* Qh = hs_bf;                          // [B][32][S][128]
  ushort* Kh = wq_bf;                          // [B][8][S][128]
  ushort* Vt = (ushort*)(ws + 41943040);       // [B][8][128][S]
  ushort* attn_out = q_lin;                    // [4096][4096]

  // one fused conversion: outputs hs_bf|wq_bf|wk_bf|wv_bf|wo_bf are contiguous
  f2bf5_kernel<<<57344, 256, 0, stream>>>((const float4*)hs, (const float4*)wq,
                                          (const float4*)wk, (const float4*)wv,
                                          (const float4*)wo, (ushort4*)ws);

  gemm256_kernel<0><<<256, 512, 0, stream>>>(hs_bf, wq_bf, q_lin, 4096, 4096, 4096);
  // fused K+V projection: B = [wk;wv] (contiguous), N=2048
  gemm_bt_kernel<0><<<dim3(16, 32), 256, 0, stream>>>(hs_bf, wk_bf, kv_lin, 4096, 2048, 4096);

  // merged rope-Q + rope-K + V-transpose (Q pre-scale folds 1/sqrt(128)*log2e)
  relayout_kernel<<<41984, 256, 0, stream>>>(q_lin, kv_lin, cosb, sinb, Qh, Kh, Vt,
                                             0.08838834764831845f * 1.4426950408889634f);

  attn_kernel<<<512, 512, 0, stream>>>(Qh, Kh, Vt, attn_out);

  gemm256_kernel<1><<<256, 512, 0, stream>>>(attn_out, wo_bf, d_out, 4096, 4096, 4096);
}